// Round 8
// baseline (261.693 us; speedup 1.0000x reference)
//
#include <hip/hip_runtime.h>
#include <math.h>

#define NB 2048
#define NF 42
#define NC 521

// BRUX_COMBOS flattened: 13 combos x 3 (class, lo, hi)
__constant__ int   d_ccls[39] = {
    500, 41,  0,
    369, 500, 0,
    412, 431, 470,
    127, 67,  103,
    399, 403, 412,
    410, 411, 398,
    412, 410, 398,
    435, 438, 449,
    374, 436, 435,
    372, 434, 469,
    500, 439, 50,
    399, 403, 410,
    410, 398, 435};
__constant__ float d_clo[39] = {
    0.1f, 0.05f, 0.0f,
    0.1f, 0.1f,  0.0f,
    0.05f,0.05f, 0.05f,
    0.1f, 0.1f,  0.1f,
    0.1f, 0.1f,  0.1f,
    0.1f, 0.1f,  0.1f,
    0.1f, 0.1f,  0.1f,
    0.1f, 0.1f,  0.1f,
    0.1f, 0.1f,  0.1f,
    0.1f, 0.1f,  0.1f,
    0.1f, 0.1f,  0.1f,
    0.1f, 0.1f,  0.1f,
    0.1f, 0.1f,  0.1f};
__constant__ float d_chi[39] = {
    0.8f, 0.5f, 1.0f,
    0.5f, 0.5f, 1.0f,
    0.4f, 0.4f, 0.4f,
    0.8f, 0.7f, 0.6f,
    0.9f, 0.8f, 0.7f,
    0.9f, 0.8f, 0.7f,
    0.8f, 0.7f, 0.6f,
    0.9f, 0.8f, 0.7f,
    0.9f, 0.8f, 0.7f,
    0.9f, 0.8f, 0.7f,
    0.8f, 0.7f, 0.6f,
    0.9f, 0.8f, 0.7f,
    0.9f, 0.8f, 0.7f};
// round(score*100)/100 in f32 is identity for these constants
__constant__ float d_btab[13] = {2.94f, 1.76f, 1.76f, 1.47f, 0.29f, 0.88f, 0.01f,
                                 0.29f, 0.29f, 0.01f, 0.29f, 0.01f, 0.01f};

struct Row {
    float vv[8];       // stream: row[lane + 64k]
    float tail;        // row[512 + min(lane,8)] (masked to 0 in classify for lane>=9)
    float a0, a1, a2;  // combo gather values (clamped lane for lane>=13)
};

// All loads branchless (clamped indices) -> no exec-mask churn in the load cluster,
// maximally hoistable/pipelinable. 12 VMEM ops per row.
__device__ __forceinline__ void row_load(const float* __restrict__ row, int lane, Row& r) {
#pragma unroll
    for (int k = 0; k < 8; ++k) r.vv[k] = row[lane + (k << 6)];
    r.tail = row[512 + (lane < 9 ? lane : 8)];
    const int c3 = (lane < 13 ? lane : 0) * 3;
    r.a0 = row[d_ccls[c3 + 0]];
    r.a1 = row[d_ccls[c3 + 1]];
    r.a2 = row[d_ccls[c3 + 2]];
}

__device__ __forceinline__ void row_classify(const Row& r, int lane, int f,
                                             int* s_bfj, float* s_bfs,
                                             int* s_cfj, float* s_cfs) {
    // pivots via shuffle: lane j of vv[0] holds row[j]  (no extra loads)
    const float v0  = __shfl(r.vv[0], 0);
    const float v38 = __shfl(r.vv[0], 38);
    const float v42 = __shfl(r.vv[0], 42);
    const float tl  = (lane < 9) ? r.tail : 0.0f;  // pivots in [0,1): 0.0 contributes nothing

    // packed rank counters: rank0 | rank38<<10 | rank42<<20 (each total <= 521 < 1024)
    int cnt;
    {   // k = 0: j = lane in [0,64) -> stable tie-break (j < c) can apply
        const float v = r.vv[0];
        cnt = (int)(v > v0)
            + ((int)((v > v38) || ((v == v38) && (lane < 38))) << 10)
            + ((int)((v > v42) || ((v == v42) && (lane < 42))) << 20);
    }
#pragma unroll
    for (int k = 1; k < 8; ++k) {  // j >= 64 > 42: tie-break never applies
        const float v = r.vv[k];
        cnt += (int)(v > v0) + ((int)(v > v38) << 10) + ((int)(v > v42) << 20);
    }
    cnt += (int)(tl > v0) + ((int)(tl > v38) << 10) + ((int)(tl > v42) << 20);

#pragma unroll
    for (int s = 32; s > 0; s >>= 1) cnt += __shfl_xor(cnt, s);

    const bool in0  = (cnt & 1023) < 10;          // rank<10 <=> in top-10 (stable ties)
    const bool in38 = ((cnt >> 10) & 1023) < 10;
    const bool in42 = ((cnt >> 20) & 1023) < 10;
    const bool has_nb = in0 || in38 || in42;

    bool pass = false;
    if (lane < 13) {
        const int c3 = lane * 3;
        pass = (r.a0 >= d_clo[c3 + 0]) & (r.a0 <= d_chi[c3 + 0]) &
               (r.a1 >= d_clo[c3 + 1]) & (r.a1 <= d_chi[c3 + 1]) &
               (r.a2 >= d_clo[c3 + 2]) & (r.a2 <= d_chi[c3 + 2]);
    }
    const unsigned long long cm = __ballot(pass);
    const bool any   = (cm != 0ull);
    const int  first = any ? __builtin_ctzll(cm) : 0;

    const bool  bfj = any && !has_nb;
    const float bfs = bfj ? d_btab[first] : 0.0f;

    const bool  cpass = (v42 >= 0.1f) && (v42 <= 1.0f);
    const bool  cfj   = cpass || in42;
    const float cfs   = cpass ? 1.5f : (in42 ? 1.0f : 0.0f);

    if (lane == 0) {
        s_bfj[f] = (int)bfj;
        s_bfs[f] = bfs;
        s_cfj[f] = (int)cfj;
        s_cfs[f] = cfs;
    }
}

__global__ __launch_bounds__(256, 8)
void sleep_cls_kernel(const float* __restrict__ score, float* __restrict__ out) {
    const int b    = blockIdx.x;
    const int tid  = threadIdx.x;
    const int wave = tid >> 6;
    const int lane = tid & 63;
    const float* base = score + (size_t)b * (NF * NC);

    __shared__ int   s_bfj[NF];
    __shared__ float s_bfs[NF];
    __shared__ int   s_cfj[NF];
    __shared__ float s_cfs[NF];

    // ---- stage 1: stride-4 interleave (block's 4 waves touch consecutive rows:
    // good L2/DRAM page locality), ping-pong 1-deep prefetch: row f+4's loads are
    // in flight while row f's shuffle-chain runs.
    int f = wave;
    Row A, B;
    row_load(base + f * NC, lane, A);
    for (;;) {
        const int f2 = f + 4;
        if (f2 < NF) {
            row_load(base + f2 * NC, lane, B);
            row_classify(A, lane, f, s_bfj, s_bfs, s_cfj, s_cfs);
            const int f3 = f2 + 4;
            if (f3 < NF) {
                row_load(base + f3 * NC, lane, A);
                row_classify(B, lane, f2, s_bfj, s_bfs, s_cfj, s_cfs);
                f = f3;
                continue;
            }
            row_classify(B, lane, f2, s_bfj, s_bfs, s_cfj, s_cfs);
            break;
        }
        row_classify(A, lane, f, s_bfj, s_bfs, s_cfj, s_cfs);
        break;
    }
    __syncthreads();

    // ---- stage 2: windowed group classification
    // wave 0: brux  (gsize=4, R=39, min_valid=2, required=2)
    // wave 1: cough (gsize=3, R=40, min_valid=2, required=2)
    if (wave < 2) {
        const int R = (wave == 0) ? 39 : 40;
        const int G = (wave == 0) ? 4 : 3;
        const int*   jarr = (wave == 0) ? s_bfj : s_cfj;
        const float* sarr = (wave == 0) ? s_bfs : s_cfs;

        bool  gj = false;
        float gs = -INFINITY;
        if (lane < R) {
            int   tc = 0;
            float ss = 0.0f;
            for (int k = 0; k < G; ++k) {  // scores are 0 where !judged, so plain sum
                tc += jarr[lane + k];
                ss += sarr[lane + k];
            }
            gj = (tc >= 2);
            gs = gj ? ss : -INFINITY;
        }
        const unsigned long long jm = __ballot(gj);
        const bool ok = __popcll(jm) >= 2;

        float m1 = gs;
#pragma unroll
        for (int s = 32; s > 0; s >>= 1) m1 = fmaxf(m1, __shfl_xor(m1, s));
        const unsigned long long em = __ballot(gs == m1);  // nonzero (-inf==-inf)
        const int amax = __builtin_ctzll(em);
        float gs2 = (lane == amax) ? -INFINITY : gs;
        float m2 = gs2;
#pragma unroll
        for (int s = 32; s > 0; s >>= 1) m2 = fmaxf(m2, __shfl_xor(m2, s));

        if (lane == 0) {
            const int jo = (wave == 0) ? 0 : 2 * NB;
            const int so = (wave == 0) ? NB : 3 * NB;
            out[jo + b] = ok ? 1.0f : 0.0f;
            out[so + b] = ok ? (m1 + m2) : 0.0f;
        }
    }
}

extern "C" void kernel_launch(void* const* d_in, const int* in_sizes, int n_in,
                              void* d_out, int out_size, void* d_ws, size_t ws_size,
                              hipStream_t stream) {
    const float* score = (const float*)d_in[0];
    float* out = (float*)d_out;
    sleep_cls_kernel<<<dim3(NB), dim3(256), 0, stream>>>(score, out);
}

// Round 12
// 238.469 us; speedup vs baseline: 1.0974x; 1.0974x over previous
//
#include <hip/hip_runtime.h>
#include <math.h>

#define NB 2048
#define NF 42
#define NC 521
#define NROWS (NB * NF)   // 86016

// BRUX_COMBOS flattened: 13 combos x 3 (class, lo, hi)
__constant__ int   d_ccls[39] = {
    500, 41,  0,
    369, 500, 0,
    412, 431, 470,
    127, 67,  103,
    399, 403, 412,
    410, 411, 398,
    412, 410, 398,
    435, 438, 449,
    374, 436, 435,
    372, 434, 469,
    500, 439, 50,
    399, 403, 410,
    410, 398, 435};
__constant__ float d_clo[39] = {
    0.1f, 0.05f, 0.0f,
    0.1f, 0.1f,  0.0f,
    0.05f,0.05f, 0.05f,
    0.1f, 0.1f,  0.1f,
    0.1f, 0.1f,  0.1f,
    0.1f, 0.1f,  0.1f,
    0.1f, 0.1f,  0.1f,
    0.1f, 0.1f,  0.1f,
    0.1f, 0.1f,  0.1f,
    0.1f, 0.1f,  0.1f,
    0.1f, 0.1f,  0.1f,
    0.1f, 0.1f,  0.1f,
    0.1f, 0.1f,  0.1f};
__constant__ float d_chi[39] = {
    0.8f, 0.5f, 1.0f,
    0.5f, 0.5f, 1.0f,
    0.4f, 0.4f, 0.4f,
    0.8f, 0.7f, 0.6f,
    0.9f, 0.8f, 0.7f,
    0.9f, 0.8f, 0.7f,
    0.8f, 0.7f, 0.6f,
    0.9f, 0.8f, 0.7f,
    0.9f, 0.8f, 0.7f,
    0.9f, 0.8f, 0.7f,
    0.8f, 0.7f, 0.6f,
    0.9f, 0.8f, 0.7f,
    0.9f, 0.8f, 0.7f};
// round(score*100)/100 in f32 is identity for these constants
__constant__ float d_btab[13] = {2.94f, 1.76f, 1.76f, 1.47f, 0.29f, 0.88f, 0.01f,
                                 0.29f, 0.29f, 0.01f, 0.29f, 0.01f, 0.01f};

// ---- kernel 1: one wave per (batch,frame) row. No loops, no LDS, minimal
// register lifetime -> ~30 VGPR, 32 waves/CU pure TLP. Consecutive waves read
// consecutive rows (linear sweep, fill-like page behavior).
__global__ __launch_bounds__(256, 8)
void frame_kernel(const float* __restrict__ score, float4* __restrict__ ws) {
    const int wave = threadIdx.x >> 6;
    const int lane = threadIdx.x & 63;
    const int gid  = blockIdx.x * 4 + wave;          // row id in [0, 86016)
    const float* row = score + (size_t)gid * NC;

    // 12 branchless loads, all independent
    float vv[8];
#pragma unroll
    for (int k = 0; k < 8; ++k) vv[k] = row[lane + (k << 6)];
    const float tail = row[512 + (lane < 9 ? lane : 8)];
    const int c3 = (lane < 13 ? lane : 0) * 3;
    const float a0 = row[d_ccls[c3 + 0]];
    const float a1 = row[d_ccls[c3 + 1]];
    const float a2 = row[d_ccls[c3 + 2]];

    // pivots via shuffle: lane j of vv[0] holds row[j]
    const float v0  = __shfl(vv[0], 0);
    const float v38 = __shfl(vv[0], 38);
    const float v42 = __shfl(vv[0], 42);
    const float tl  = (lane < 9) ? tail : 0.0f;      // pivots in [0,1): 0.0 inert

    // packed rank counters: rank0 | rank38<<10 | rank42<<20 (totals <= 521 < 1024)
    int cnt;
    {   // j = lane < 64: stable tie-break (j < c) can apply
        const float v = vv[0];
        cnt = (int)(v > v0)
            + ((int)((v > v38) || ((v == v38) && (lane < 38))) << 10)
            + ((int)((v > v42) || ((v == v42) && (lane < 42))) << 20);
    }
#pragma unroll
    for (int k = 1; k < 8; ++k) {                    // j >= 64 > 42: no tie-break
        const float v = vv[k];
        cnt += (int)(v > v0) + ((int)(v > v38) << 10) + ((int)(v > v42) << 20);
    }
    cnt += (int)(tl > v0) + ((int)(tl > v38) << 10) + ((int)(tl > v42) << 20);
#pragma unroll
    for (int s = 32; s > 0; s >>= 1) cnt += __shfl_xor(cnt, s);

    const bool in0  = (cnt & 1023) < 10;             // rank<10 <=> in top-10 (stable)
    const bool in38 = ((cnt >> 10) & 1023) < 10;
    const bool in42 = ((cnt >> 20) & 1023) < 10;
    const bool has_nb = in0 || in38 || in42;

    bool pass = false;
    if (lane < 13) {
        pass = (a0 >= d_clo[c3 + 0]) & (a0 <= d_chi[c3 + 0]) &
               (a1 >= d_clo[c3 + 1]) & (a1 <= d_chi[c3 + 1]) &
               (a2 >= d_clo[c3 + 2]) & (a2 <= d_chi[c3 + 2]);
    }
    const unsigned long long cm = __ballot(pass);
    const bool any   = (cm != 0ull);
    const int  first = any ? __builtin_ctzll(cm) : 0;

    const bool  bfj = any && !has_nb;
    const float bfs = bfj ? d_btab[first] : 0.0f;

    const bool  cpass = (v42 >= 0.1f) && (v42 <= 1.0f);
    const bool  cfj   = cpass || in42;
    const float cfs   = cpass ? 1.5f : (in42 ? 1.0f : 0.0f);

    if (lane == 0)
        ws[gid] = make_float4(bfj ? 1.0f : 0.0f, bfs, cfj ? 1.0f : 0.0f, cfs);
}

// ---- kernel 2: one wave per batch item; both window classifies in-register.
__global__ __launch_bounds__(256)
void group_kernel(const float4* __restrict__ ws, float* __restrict__ out) {
    const int wave = threadIdx.x >> 6;
    const int lane = threadIdx.x & 63;
    const int b    = blockIdx.x * 4 + wave;          // [0, 2048)

    float4 v = make_float4(0.0f, 0.0f, 0.0f, 0.0f);
    if (lane < NF) v = ws[b * NF + lane];
    const float bfj = v.x, bfs = v.y, cfj = v.z, cfs = v.w;

    // brux: gsize=4, R=39, min_valid=2, required=2
    {
        const float j1 = __shfl_down(bfj, 1), j2 = __shfl_down(bfj, 2), j3 = __shfl_down(bfj, 3);
        const float s1 = __shfl_down(bfs, 1), s2 = __shfl_down(bfs, 2), s3 = __shfl_down(bfs, 3);
        const float tc = ((bfj + j1) + j2) + j3;     // integral floats, exact
        const float ss = ((bfs + s1) + s2) + s3;     // same add order as before (absmax 0.0)
        const bool  gj = (lane < 39) && (tc >= 2.0f);
        float gs = gj ? ss : -INFINITY;

        const unsigned long long jm = __ballot(gj);
        const bool ok = __popcll(jm) >= 2;
        float m1 = gs;
#pragma unroll
        for (int s = 32; s > 0; s >>= 1) m1 = fmaxf(m1, __shfl_xor(m1, s));
        const unsigned long long em = __ballot(gs == m1);
        const int amax = __builtin_ctzll(em);
        float m2 = (lane == amax) ? -INFINITY : gs;
#pragma unroll
        for (int s = 32; s > 0; s >>= 1) m2 = fmaxf(m2, __shfl_xor(m2, s));

        if (lane == 0) {
            out[b]      = ok ? 1.0f : 0.0f;
            out[NB + b] = ok ? (m1 + m2) : 0.0f;
        }
    }

    // cough: gsize=3, R=40, min_valid=2, required=2
    {
        const float j1 = __shfl_down(cfj, 1), j2 = __shfl_down(cfj, 2);
        const float s1 = __shfl_down(cfs, 1), s2 = __shfl_down(cfs, 2);
        const float tc = (cfj + j1) + j2;
        const float ss = (cfs + s1) + s2;
        const bool  gj = (lane < 40) && (tc >= 2.0f);
        float gs = gj ? ss : -INFINITY;

        const unsigned long long jm = __ballot(gj);
        const bool ok = __popcll(jm) >= 2;
        float m1 = gs;
#pragma unroll
        for (int s = 32; s > 0; s >>= 1) m1 = fmaxf(m1, __shfl_xor(m1, s));
        const unsigned long long em = __ballot(gs == m1);
        const int amax = __builtin_ctzll(em);
        float m2 = (lane == amax) ? -INFINITY : gs;
#pragma unroll
        for (int s = 32; s > 0; s >>= 1) m2 = fmaxf(m2, __shfl_xor(m2, s));

        if (lane == 0) {
            out[2 * NB + b] = ok ? 1.0f : 0.0f;
            out[3 * NB + b] = ok ? (m1 + m2) : 0.0f;
        }
    }
}

extern "C" void kernel_launch(void* const* d_in, const int* in_sizes, int n_in,
                              void* d_out, int out_size, void* d_ws, size_t ws_size,
                              hipStream_t stream) {
    const float* score = (const float*)d_in[0];
    float* out = (float*)d_out;
    float4* ws = (float4*)d_ws;                       // 86016 * 16B = 1.4 MB used
    frame_kernel<<<dim3(NROWS / 4), dim3(256), 0, stream>>>(score, ws);
    group_kernel<<<dim3(NB / 4), dim3(256), 0, stream>>>(ws, out);
}